// Round 4
// baseline (242.287 us; speedup 1.0000x reference)
//
#include <hip/hip_runtime.h>
#include <math.h>

#define N 1024
#define NM1 1023
#define DIM 128
#define LAMB 0.9f
#define INV2SIG2 (1.0f / 450.0f)   // 0.5 / sigma^2, sigma=15

typedef short v8s __attribute__((ext_vector_type(8)));
typedef float v4f __attribute__((ext_vector_type(4)));

__device__ __forceinline__ unsigned short f2bf(float x) {   // RNE float->bf16
    unsigned int u = __float_as_uint(x);
    u += 0x7FFFu + ((u >> 16) & 1u);
    return (unsigned short)(u >> 16);
}
__device__ __forceinline__ float bf2f(unsigned short h) {
    return __uint_as_float(((unsigned int)h) << 16);
}

// ---------------- compose A: S=W3*W2 | R=W1*W4 | t1=W3 b2+b3, t2=W1 b4 | zero-init ---
__global__ __launch_bounds__(256) void k_compose_a(
    const float* __restrict__ w1, const float* __restrict__ w3,
    const float* __restrict__ w2, const float* __restrict__ w4,
    const float* __restrict__ b2, const float* __restrict__ b3,
    const float* __restrict__ b4,
    float* __restrict__ S, float* __restrict__ R,
    float* __restrict__ t1v, float* __restrict__ t2v,
    float* __restrict__ zeros)   // fn2/mag/total contiguous, 3072 floats
{
    const int b = blockIdx.x;
    const int t = threadIdx.x;
    if (b < 64) {                       // S[i][j] = sum_k W3[i,k] W2[k,j]
        const int i = 2 * b + (t >> 7), j = t & 127;
        float acc = 0.f;
        #pragma unroll 8
        for (int k = 0; k < 128; ++k) acc += w3[i * 128 + k] * w2[k * 128 + j];
        S[i * 128 + j] = acc;
    } else if (b < 128) {               // R[i][j] = sum_k W1[i,k] W4[k,j]
        const int i = 2 * (b - 64) + (t >> 7), j = t & 127;
        float acc = 0.f;
        #pragma unroll 8
        for (int k = 0; k < 128; ++k) acc += w1[i * 128 + k] * w4[k * 128 + j];
        R[i * 128 + j] = acc;
    } else if (b == 128) {
        if (t < 128) {                  // t1 = W3 b2 + b3
            float acc = b3[t];
            #pragma unroll 8
            for (int k = 0; k < 128; ++k) acc += w3[t * 128 + k] * b2[k];
            t1v[t] = acc;
        } else {                        // t2 = W1 b4
            const int i = t - 128;
            float acc = 0.f;
            #pragma unroll 8
            for (int k = 0; k < 128; ++k) acc += w1[i * 128 + k] * b4[k];
            t2v[i] = acc;
        }
    } else {                            // zero fn2/mag/total
        #pragma unroll
        for (int s = 0; s < 12; ++s) zeros[t + 256 * s] = 0.f;
    }
}

// ---------------- compose B: G=W4*S | X=R*S | bg=W4 t1+b4, bx=R t1+t2+b1 ------------
__global__ __launch_bounds__(256) void k_compose_b(
    const float* __restrict__ w4, const float* __restrict__ S,
    const float* __restrict__ R,
    const float* __restrict__ t1v, const float* __restrict__ t2v,
    const float* __restrict__ b1, const float* __restrict__ b4,
    float* __restrict__ Wboth, float* __restrict__ bboth)
{
    const int b = blockIdx.x;
    const int t = threadIdx.x;
    if (b < 64) {                       // G rows 0-127 of Wboth
        const int i = 2 * b + (t >> 7), j = t & 127;
        float acc = 0.f;
        #pragma unroll 8
        for (int k = 0; k < 128; ++k) acc += w4[i * 128 + k] * S[k * 128 + j];
        Wboth[i * 128 + j] = acc;
    } else if (b < 128) {               // X rows 128-255 of Wboth
        const int i = 2 * (b - 64) + (t >> 7), j = t & 127;
        float acc = 0.f;
        #pragma unroll 8
        for (int k = 0; k < 128; ++k) acc += R[i * 128 + k] * S[k * 128 + j];
        Wboth[(128 + i) * 128 + j] = acc;
    } else {
        if (t < 128) {                  // bg = W4 t1 + b4
            float acc = b4[t];
            #pragma unroll 8
            for (int k = 0; k < 128; ++k) acc += w4[t * 128 + k] * t1v[k];
            bboth[t] = acc;
        } else {                        // bx = R t1 + t2 + b1
            const int i = t - 128;
            float acc = t2v[i] + b1[i];
            #pragma unroll 8
            for (int k = 0; k < 128; ++k) acc += R[i * 128 + k] * t1v[k];
            bboth[128 + i] = acc;
        }
    }
}

// ---------------- K1: Y = f @ Wboth^T + bboth; xb (bf16) + fn2/mag ----------
__global__ __launch_bounds__(256) void k_gemm(
    const float* __restrict__ f, const float* __restrict__ Wb,
    const float* __restrict__ bb,
    unsigned short* __restrict__ xb, float* __restrict__ fn2, float* __restrict__ mag)
{
    __shared__ float4 fl4[64][33];
    __shared__ float4 wl4[64][33];
    __shared__ float bsh[64];
    const int t = threadIdx.x;
    const int row0 = blockIdx.y * 64;
    const int col0 = blockIdx.x * 64;   // over 256 outputs
    const float4* F4 = (const float4*)f;
    const float4* W4p = (const float4*)Wb;

    #pragma unroll
    for (int s = 0; s < 8; ++s) {
        int idx = t + 256 * s;
        int r = idx >> 5, k4 = idx & 31;
        fl4[r][k4] = F4[(row0 + r) * 32 + k4];
        wl4[r][k4] = W4p[(col0 + r) * 32 + k4];
    }
    if (t < 64) bsh[t] = bb[col0 + t];
    __syncthreads();

    const int tx = t & 15, ty = t >> 4;
    float acc[4][4];
    #pragma unroll
    for (int i = 0; i < 4; ++i)
        #pragma unroll
        for (int j = 0; j < 4; ++j) acc[i][j] = 0.f;

    for (int k4 = 0; k4 < 32; ++k4) {
        float4 fa[4], wv[4];
        #pragma unroll
        for (int i = 0; i < 4; ++i) fa[i] = fl4[ty + 16 * i][k4];
        #pragma unroll
        for (int j = 0; j < 4; ++j) wv[j] = wl4[tx + 16 * j][k4];
        #pragma unroll
        for (int i = 0; i < 4; ++i)
            #pragma unroll
            for (int j = 0; j < 4; ++j)
                acc[i][j] += fa[i].x * wv[j].x + fa[i].y * wv[j].y
                           + fa[i].z * wv[j].z + fa[i].w * wv[j].w;
    }

    const bool isg = (col0 < 128);
    #pragma unroll
    for (int i = 0; i < 4; ++i) {
        int gr = row0 + ty + 16 * i;
        float ss = 0.f;
        #pragma unroll
        for (int j = 0; j < 4; ++j) {
            int c = tx + 16 * j;
            float yv = acc[i][j] + bsh[c];
            ss += yv * yv;
            if (!isg) xb[gr * DIM + (col0 - 128) + c] = f2bf(yv);
        }
        #pragma unroll
        for (int off = 1; off < 16; off <<= 1) ss += __shfl_xor(ss, off, 64);
        if (tx == 0) atomicAdd(isg ? &fn2[gr] : &mag[gr], ss);
    }
}

// ---------------- K2: MFMA affinity A = exp(-(S-1)^2 fn2_j/450), diag 0, totals ----
__global__ __launch_bounds__(512) void k_aff(
    const unsigned short* __restrict__ xb, const float* __restrict__ mag,
    const float* __restrict__ fn2, float* __restrict__ A,
    float* __restrict__ total)
{
    const int t = threadIdx.x;
    const int wave = t >> 6, lane = t & 63;
    const int wm = wave >> 1, wn = wave & 1;
    const int l15 = lane & 15, quad = lane >> 4;
    const int i0 = blockIdx.y * 64, j0 = blockIdx.x * 64;

    const unsigned short* ar  = xb + (i0 + wm * 16 + l15) * DIM + quad * 8;
    const unsigned short* b0r = xb + (j0 + wn * 32 + l15) * DIM + quad * 8;
    const unsigned short* b1r = b0r + 16 * DIM;

    v4f acc0 = {0.f, 0.f, 0.f, 0.f}, acc1 = {0.f, 0.f, 0.f, 0.f};
    #pragma unroll
    for (int kc = 0; kc < 4; ++kc) {
        v8s a  = *(const v8s*)(ar  + kc * 32);
        v8s b0 = *(const v8s*)(b0r + kc * 32);
        v8s b1 = *(const v8s*)(b1r + kc * 32);
        acc0 = __builtin_amdgcn_mfma_f32_16x16x32_bf16(a, b0, acc0, 0, 0, 0);
        acc1 = __builtin_amdgcn_mfma_f32_16x16x32_bf16(a, b1, acc1, 0, 0, 0);
    }

    const int gj0 = j0 + wn * 32 + l15;
    const int gj1 = gj0 + 16;
    const float rm0 = 1.0f / mag[gj0], rm1 = 1.0f / mag[gj1];
    const float fj0 = fn2[gj0] * INV2SIG2, fj1 = fn2[gj1] * INV2SIG2;

    #pragma unroll
    for (int reg = 0; reg < 4; ++reg) {
        int gi = i0 + wm * 16 + quad * 4 + reg;
        float S0 = acc0[reg] * rm0 - 1.0f;
        float S1 = acc1[reg] * rm1 - 1.0f;
        float a0 = (gi == gj0) ? 0.f : __expf(-(S0 * S0) * fj0);
        float a1 = (gi == gj1) ? 0.f : __expf(-(S1 * S1) * fj1);
        A[gi * N + gj0] = a0;
        A[gi * N + gj1] = a1;
        float s = a0 + a1;
        #pragma unroll
        for (int off = 1; off < 16; off <<= 1) s += __shfl_xor(s, off, 64);
        if (l15 == 0) atomicAdd(&total[gi], s);
    }
}

// ---------------- K3: Bb = bf16(lambda * A[i][j]/total_i), row0/col0 = 0; + BbT; + P0f
__global__ __launch_bounds__(256) void k_makeB(
    const float* __restrict__ A, const float* __restrict__ total,
    unsigned short* __restrict__ Bb, unsigned short* __restrict__ BbT,
    float* __restrict__ P0f)
{
    __shared__ unsigned short Lt[64][65];
    const int t = threadIdx.x;
    const int i0 = blockIdx.y * 64, j0 = blockIdx.x * 64;
    const int r = t >> 2, c0 = (t & 3) * 16;
    const int gi = i0 + r;
    const float rt = LAMB / fmaxf(total[gi], 1e-10f);

    const float4* Ar = (const float4*)(A + gi * N + j0 + c0);
    unsigned short ob[16];
    #pragma unroll
    for (int q = 0; q < 4; ++q) {
        float4 av = Ar[q];
        float vv[4] = {av.x, av.y, av.z, av.w};
        #pragma unroll
        for (int e = 0; e < 4; ++e) {
            int gj = j0 + c0 + 4 * q + e;
            float val = (gi >= 1 && gj >= 1) ? vv[e] * rt : 0.f;
            ob[4 * q + e] = f2bf(val);
        }
    }
    uint4 p0, p1;
    unsigned short* pp0 = (unsigned short*)&p0;
    unsigned short* pp1 = (unsigned short*)&p1;
    #pragma unroll
    for (int e = 0; e < 8; ++e) { pp0[e] = ob[e]; pp1[e] = ob[8 + e]; }
    *(uint4*)(Bb + gi * N + j0 + c0)     = p0;
    *(uint4*)(Bb + gi * N + j0 + c0 + 8) = p1;
    #pragma unroll
    for (int e = 0; e < 16; ++e) Lt[r][c0 + e] = ob[e];

    if (blockIdx.y == 0 && t < 64) {
        int gj = j0 + t;
        P0f[gj] = (gj == 0) ? 0.f : A[gj] / fmaxf(total[0], 1e-10f);
    }
    __syncthreads();

    const int c = t >> 2, r0 = (t & 3) * 16;
    uint4 q0, q1;
    unsigned short* qq0 = (unsigned short*)&q0;
    unsigned short* qq1 = (unsigned short*)&q1;
    #pragma unroll
    for (int e = 0; e < 8; ++e) { qq0[e] = Lt[r0 + e][c]; qq1[e] = Lt[r0 + 8 + e][c]; }
    *(uint4*)(BbT + (j0 + c) * N + i0 + r0)     = q0;
    *(uint4*)(BbT + (j0 + c) * N + i0 + r0 + 8) = q1;
}

// ---------------- K4: generic bf16 MFMA GEMM: C = A*(Bt^T) [+add0 +add1 +diag] ------
// Dual-job launch: blockIdx.z selects param set. Prefetch depth 4.
struct MMArgs {
    const unsigned short* A;     // A rows
    const unsigned short* Bt;    // rows of B^T
    const unsigned short* add0;  // optional elementwise add (bf16), may be null
    const unsigned short* add1;  // optional elementwise add (bf16), may be null
    int adddiag;                 // add identity?
    unsigned short* C;           // output rows
    unsigned short* CT;          // optional transposed output, may be null
};

__global__ __launch_bounds__(512) void k_mm(MMArgs pa, MMArgs pb)
{
    __shared__ unsigned short Lt[64][65];
    const MMArgs p = (blockIdx.z == 0) ? pa : pb;
    const int t = threadIdx.x;
    const int wave = t >> 6, lane = t & 63;
    const int wm = wave >> 1, wn = wave & 1;
    const int l15 = lane & 15, quad = lane >> 4;
    const int i0 = blockIdx.y * 64, j0 = blockIdx.x * 64;

    const unsigned short* ar  = p.A  + (i0 + wm * 16 + l15) * N + quad * 8;
    const unsigned short* b0r = p.Bt + (j0 + wn * 32 + l15) * N + quad * 8;
    const unsigned short* b1r = b0r + 16 * N;

    v8s abuf[4], b0buf[4], b1buf[4];
    #pragma unroll
    for (int q = 0; q < 4; ++q) {
        abuf[q]  = *(const v8s*)(ar  + q * 32);
        b0buf[q] = *(const v8s*)(b0r + q * 32);
        b1buf[q] = *(const v8s*)(b1r + q * 32);
    }
    v4f acc0 = {0.f, 0.f, 0.f, 0.f}, acc1 = {0.f, 0.f, 0.f, 0.f};
    #pragma unroll
    for (int kc = 0; kc < 32; ++kc) {
        const int s = kc & 3;
        v8s a = abuf[s], b0 = b0buf[s], b1 = b1buf[s];
        if (kc + 4 < 32) {
            abuf[s]  = *(const v8s*)(ar  + (kc + 4) * 32);
            b0buf[s] = *(const v8s*)(b0r + (kc + 4) * 32);
            b1buf[s] = *(const v8s*)(b1r + (kc + 4) * 32);
        }
        acc0 = __builtin_amdgcn_mfma_f32_16x16x32_bf16(a, b0, acc0, 0, 0, 0);
        acc1 = __builtin_amdgcn_mfma_f32_16x16x32_bf16(a, b1, acc1, 0, 0, 0);
    }

    #pragma unroll
    for (int tn = 0; tn < 2; ++tn) {
        int col = wn * 32 + tn * 16 + l15;
        #pragma unroll
        for (int reg = 0; reg < 4; ++reg) {
            int row = wm * 16 + quad * 4 + reg;
            float vv = tn ? acc1[reg] : acc0[reg];
            int gidx = (i0 + row) * N + j0 + col;
            if (p.add0) vv += bf2f(p.add0[gidx]);
            if (p.add1) vv += bf2f(p.add1[gidx]);
            if (p.adddiag && (i0 + row == j0 + col)) vv += 1.0f;
            unsigned short hb = f2bf(vv);
            p.C[gidx] = hb;
            Lt[row][col] = hb;
        }
    }
    if (p.CT) {
        __syncthreads();
        const int c = t >> 3, r0 = (t & 7) * 8;
        uint4 q;
        unsigned short* qq = (unsigned short*)&q;
        #pragma unroll
        for (int e = 0; e < 8; ++e) qq[e] = Lt[r0 + e][c];
        *(uint4*)(p.CT + (j0 + c) * N + i0 + r0) = q;
    }
}

// ---------------- K5: v[r] = base[r] + (M z)[r], bf16 matrix; base may be null ------
__global__ __launch_bounds__(256) void k_mvb(
    const unsigned short* __restrict__ M, const float* __restrict__ base,
    const float* __restrict__ z, float* __restrict__ v)
{
    const int r = (blockIdx.x * 256 + threadIdx.x) >> 6;
    const int lane = threadIdx.x & 63;
    const uint4* m4 = (const uint4*)(M + r * N + lane * 16);
    const float4* z4 = (const float4*)(z + lane * 16);
    uint4 ma = m4[0], mb = m4[1];
    float4 z0 = z4[0], z1 = z4[1], z2 = z4[2], z3 = z4[3];
    float acc = 0.f;
    acc += bf2f((unsigned short)(ma.x)) * z0.x + bf2f((unsigned short)(ma.x >> 16)) * z0.y;
    acc += bf2f((unsigned short)(ma.y)) * z0.z + bf2f((unsigned short)(ma.y >> 16)) * z0.w;
    acc += bf2f((unsigned short)(ma.z)) * z1.x + bf2f((unsigned short)(ma.z >> 16)) * z1.y;
    acc += bf2f((unsigned short)(ma.w)) * z1.z + bf2f((unsigned short)(ma.w >> 16)) * z1.w;
    acc += bf2f((unsigned short)(mb.x)) * z2.x + bf2f((unsigned short)(mb.x >> 16)) * z2.y;
    acc += bf2f((unsigned short)(mb.y)) * z2.z + bf2f((unsigned short)(mb.y >> 16)) * z2.w;
    acc += bf2f((unsigned short)(mb.z)) * z3.x + bf2f((unsigned short)(mb.z >> 16)) * z3.y;
    acc += bf2f((unsigned short)(mb.w)) * z3.z + bf2f((unsigned short)(mb.w >> 16)) * z3.w;
    #pragma unroll
    for (int off = 32; off >= 1; off >>= 1) acc += __shfl_xor(acc, off, 64);
    if (lane == 0) v[r] = (base ? base[r] : 0.f) + acc;
}

// ---------------- K6: epilogue: P=0.1*u; center; relu*100; softmax ----------
__global__ __launch_bounds__(1024) void k_epilogue(const float* __restrict__ uf,
                                                   float* __restrict__ out)
{
    __shared__ float red[16];
    __shared__ float bval;
    const int t = threadIdx.x;
    const int wv = t >> 6, lane = t & 63;
    const bool valid = t < NM1;
    float P = valid ? 0.1f * uf[t + 1] : 0.f;

    float s = P;
    #pragma unroll
    for (int off = 32; off >= 1; off >>= 1) s += __shfl_down(s, off, 64);
    if (lane == 0) red[wv] = s;
    __syncthreads();
    if (t < 64) {
        float s2 = (t < 16) ? red[t] : 0.f;
        #pragma unroll
        for (int off = 8; off >= 1; off >>= 1) s2 += __shfl_down(s2, off, 64);
        if (t == 0) bval = s2 / 1023.0f;
    }
    __syncthreads();
    float mean = bval;
    P = valid ? fmaxf(P - mean, 0.f) * 100.f : 0.f;

    __syncthreads();
    float m = P;
    #pragma unroll
    for (int off = 32; off >= 1; off >>= 1) m = fmaxf(m, __shfl_down(m, off, 64));
    if (lane == 0) red[wv] = m;
    __syncthreads();
    if (t < 64) {
        float m2 = (t < 16) ? red[t] : 0.f;
        #pragma unroll
        for (int off = 8; off >= 1; off >>= 1) m2 = fmaxf(m2, __shfl_down(m2, off, 64));
        if (t == 0) bval = m2;
    }
    __syncthreads();
    float gmax = bval;
    float e = valid ? expf(P - gmax) : 0.f;

    __syncthreads();
    float s3 = e;
    #pragma unroll
    for (int off = 32; off >= 1; off >>= 1) s3 += __shfl_down(s3, off, 64);
    if (lane == 0) red[wv] = s3;
    __syncthreads();
    if (t < 64) {
        float s4 = (t < 16) ? red[t] : 0.f;
        #pragma unroll
        for (int off = 8; off >= 1; off >>= 1) s4 += __shfl_down(s4, off, 64);
        if (t == 0) bval = s4;
    }
    __syncthreads();
    if (valid) out[t] = e / bval;
}

extern "C" void kernel_launch(void* const* d_in, const int* in_sizes, int n_in,
                              void* d_out, int out_size, void* d_ws, size_t ws_size,
                              hipStream_t stream) {
    const float* f  = (const float*)d_in[0];
    const float* w1 = (const float*)d_in[1];
    const float* b1 = (const float*)d_in[2];
    const float* w2 = (const float*)d_in[3];
    const float* b2 = (const float*)d_in[4];
    const float* w3 = (const float*)d_in[5];
    const float* b3 = (const float*)d_in[6];
    const float* w4 = (const float*)d_in[7];
    const float* b4 = (const float*)d_in[8];
    float* ws = (float*)d_ws;

    float* A     = ws;                  // 1048576
    float* S     = ws + 1048576;        // 16384
    float* R     = ws + 1064960;        // 16384
    float* Wboth = ws + 1081344;        // 32768
    float* bboth = ws + 1114112;        // 256
    float* t1v   = ws + 1114368;        // 128
    float* t2v   = ws + 1114496;        // 128
    float* fn2   = ws + 1114624;        // 1024  (fn2/mag/total contiguous)
    float* mag   = ws + 1115648;        // 1024
    float* total = ws + 1116672;        // 1024
    float* P0f   = ws + 1117696;        // 1024
    float* t0    = ws + 1118720;        // 1024
    float* t1b   = ws + 1119744;        // 1024
    unsigned short* xb  = (unsigned short*)(ws + 1120768);  // 1024x128 bf16
    unsigned short* Bb  = (unsigned short*)(ws + 1153536);  // each mat = 524288 floats
    unsigned short* BbT = (unsigned short*)(ws + 1677824);
    unsigned short* B2  = (unsigned short*)(ws + 2202112);
    unsigned short* B2T = (unsigned short*)(ws + 2726400);
    unsigned short* B4  = (unsigned short*)(ws + 3250688);
    unsigned short* B4T = (unsigned short*)(ws + 3774976);
    unsigned short* B8  = (unsigned short*)(ws + 4299264);
    unsigned short* Q2  = (unsigned short*)(ws + 4823552);
    unsigned short* Qm  = (unsigned short*)(ws + 5347840);
    float* out = (float*)d_out;

    k_compose_a<<<130, 256, 0, stream>>>(w1, w3, w2, w4, b2, b3, b4,
                                         S, R, t1v, t2v, fn2);
    k_compose_b<<<129, 256, 0, stream>>>(w4, S, R, t1v, t2v, b1, b4, Wboth, bboth);

    k_gemm<<<dim3(4, 16), 256, 0, stream>>>(f, Wboth, bboth, xb, fn2, mag);
    k_aff<<<dim3(16, 16), 512, 0, stream>>>(xb, mag, fn2, A, total);
    k_makeB<<<dim3(16, 16), 256, 0, stream>>>(A, total, Bb, BbT, P0f);

    // L6: B2 = B*B (+T)
    MMArgs mm_b2  = {Bb, BbT, nullptr, nullptr, 0, B2, B2T};
    k_mm<<<dim3(16, 16, 1), 512, 0, stream>>>(mm_b2, mm_b2);
    // L7: B4 = B2*B2 (+T)  ||  Q2 = B*B2 + B + B2 + I
    MMArgs mm_b4  = {B2, B2T, nullptr, nullptr, 0, B4, B4T};
    MMArgs mm_q2  = {Bb, B2T, Bb, B2, 1, Q2, nullptr};
    k_mm<<<dim3(16, 16, 2), 512, 0, stream>>>(mm_b4, mm_q2);
    // L8: B8 = B4*B4  ||  Q = Q2*B4 + Q2
    MMArgs mm_b8  = {B4, B4T, nullptr, nullptr, 0, B8, nullptr};
    MMArgs mm_q   = {Q2, B4T, Q2, nullptr, 0, Qm, nullptr};
    k_mm<<<dim3(16, 16, 2), 512, 0, stream>>>(mm_b8, mm_q);

    // bracket: w = sum_{k=0}^{7} (B8)^k P0  (7 applications of w <- P0 + B8 w)
    float* zin = P0f;
    float* zout = t0;
    for (int it = 0; it < 7; ++it) {
        k_mvb<<<256, 256, 0, stream>>>(B8, P0f, zin, zout);
        zin = zout;
        zout = (zin == t0) ? t1b : t0;
    }
    // z = Q * w   (Q = (I+B)(I+B2)(I+B4))
    k_mvb<<<256, 256, 0, stream>>>(Qm, nullptr, zin, zout);

    k_epilogue<<<1, 1024, 0, stream>>>(zout, out);
}